// Round 8
// baseline (279.500 us; speedup 1.0000x reference)
//
#include <hip/hip_runtime.h>

#define D 256
#define VOCAB 4096
#define NTOT 16384      // 16 * 32 * 32
#define N_OUT0 4194304  // 16*256*32*32
#define MARGIN 0.95f

typedef _Float16 half8 __attribute__((ext_vector_type(8)));
typedef float f32x4 __attribute__((ext_vector_type(4)));

__device__ __forceinline__ void gld16(const void* g, void* l) {
    __builtin_amdgcn_global_load_lds(
        (const __attribute__((address_space(1))) void*)g,
        (__attribute__((address_space(3))) void*)l, 16, 0, 0);
}

__device__ __forceinline__ unsigned long long pack_key(float d, int v) {
    unsigned u = __float_as_uint(d);
    u ^= ((unsigned)((int)u >> 31)) | 0x80000000u;  // monotonic float->uint
    return ((unsigned long long)u << 32) | (unsigned)v;
}

// ---------------- pack ----------------
// Apk halfs: [bm 64][w 4][kk 2][q 4][r 256][j 8]   (k = w*64+kk*32+q*8+j, row = bm*256+r)
// Bpk halfs: [bn 32][w 4][kk 2][q 4][r 128][j 8]   with PERMUTED rows:
//   packed row r holds emb row v0 + (r&64) + (r&15)*4 + ((r&63)>>4)
//   so MFMA lane j16, slot nt covers v = n0 + wn*64 + j16*4 + nt
__global__ __launch_bounds__(256) void k_pack(const float* __restrict__ h,
                                              const float* __restrict__ emb,
                                              _Float16* __restrict__ Apk,
                                              _Float16* __restrict__ Bpk,
                                              float* __restrict__ esq) {
    __shared__ float S[16384];
    const int tid = threadIdx.x;
    const int bid = blockIdx.x;
    if (bid < 256) {
        const int bm = bid >> 2, w = bid & 3;
        const int b = bm >> 2, p0 = (bm & 3) << 8;
#pragma unroll 4
        for (int cl = 0; cl < 64; ++cl)
            S[cl * 256 + tid] =
                h[((size_t)b << 18) + ((size_t)(w * 64 + cl) << 10) + (size_t)(p0 + tid)];
        __syncthreads();
        _Float16* dstA = Apk + (size_t)bm * 65536 + (size_t)w * 16384;
#pragma unroll
        for (int kk = 0; kk < 2; ++kk)
#pragma unroll
            for (int q = 0; q < 4; ++q) {
                alignas(16) _Float16 hv[8];
#pragma unroll
                for (int j = 0; j < 8; ++j) hv[j] = (_Float16)S[(kk * 32 + q * 8 + j) * 256 + tid];
                *(half8*)(dstA + (kk * 4 + q) * 2048 + tid * 8) = *(half8*)hv;
            }
    } else {
        const int bn = bid - 256, v0 = bn << 7;
        float eacc = 0.f;
        _Float16* dstB = Bpk + (size_t)bn * 32768;
        const int kk = tid >> 7, r = tid & 127;
        const int sr = (r & 64) + ((r & 15) * 4) + ((r & 63) >> 4);
        for (int w = 0; w < 4; ++w) {
            __syncthreads();
#pragma unroll 4
            for (int i = 0; i < 32; ++i) {
                int rr = i * 4 + (tid >> 6), cc = tid & 63;
                S[rr * 65 + cc] = emb[(size_t)(v0 + rr) * 256 + w * 64 + cc];
            }
            __syncthreads();
            if (tid < 128)
#pragma unroll 4
                for (int cc = 0; cc < 64; ++cc) { float x = S[tid * 65 + cc]; eacc = fmaf(x, x, eacc); }
#pragma unroll
            for (int q = 0; q < 4; ++q) {
                alignas(16) _Float16 ev[8];
#pragma unroll
                for (int j = 0; j < 8; ++j) ev[j] = (_Float16)S[sr * 65 + kk * 32 + q * 8 + j];
                *(half8*)(dstB + w * 8192 + (kk * 4 + q) * 1024 + r * 8) = *(half8*)ev;
            }
        }
        if (tid < 128) esq[v0 + tid] = eacc;
    }
}

// ---------------- hi-fp16 distance GEMM + per-(row, 64-code group) float min ----------------
// top1[row*64 + bn*2 + wn] = min approx dist over codes [g*64, g*64+64)
__global__ __launch_bounds__(256, 2) void k_gemm(const _Float16* __restrict__ Apk,
                                                 const _Float16* __restrict__ Bpk,
                                                 const float* __restrict__ esq,
                                                 float* __restrict__ top1) {
    __shared__ _Float16 As[16384];  // 32 KB
    __shared__ _Float16 Bs[8192];   // 16 KB

    const int tid = threadIdx.x;
    const int bn = blockIdx.x >> 6, bm = blockIdx.x & 63;
    const int m0 = bm << 8, n0 = bn << 7;
    const int wv = tid >> 6, l = tid & 63;
    const int wm = wv & 1, wn = wv >> 1;
    const int quad = l >> 4, j16 = l & 15;

    f32x4 acc[8][4];
#pragma unroll
    for (int i = 0; i < 8; ++i)
#pragma unroll
        for (int j = 0; j < 4; ++j) acc[i][j] = (f32x4)0.0f;

    const char* Ag = (const char*)(Apk + (size_t)bm * 65536) + tid * 16;
    const char* Bg = (const char*)(Bpk + (size_t)bn * 32768) + tid * 16;
    _Float16* Asw = As + tid * 8;
    _Float16* Bsw = Bs + tid * 8;
    const _Float16* aB = As + quad * 2048 + (wm * 128 + j16) * 8;
    const _Float16* bB = Bs + quad * 1024 + (wn * 64 + j16) * 8;

    for (int w = 0; w < 4; ++w) {
#pragma unroll
        for (int i = 0; i < 8; ++i) gld16(Ag + w * 32768 + i * 4096, Asw + i * 2048);
#pragma unroll
        for (int i = 0; i < 4; ++i) gld16(Bg + w * 16384 + i * 4096, Bsw + i * 2048);
        __syncthreads();
#pragma unroll
        for (int kk = 0; kk < 2; ++kk) {
            half8 af[8], bf[4];
#pragma unroll
            for (int mt = 0; mt < 8; ++mt) af[mt] = *(const half8*)(aB + kk * 8192 + mt * 128);
#pragma unroll
            for (int nt = 0; nt < 4; ++nt) bf[nt] = *(const half8*)(bB + kk * 4096 + nt * 128);
#pragma unroll
            for (int mt = 0; mt < 8; ++mt)
#pragma unroll
                for (int nt = 0; nt < 4; ++nt)
                    acc[mt][nt] = __builtin_amdgcn_mfma_f32_16x16x32_f16(af[mt], bf[nt], acc[mt][nt], 0, 0, 0);
        }
        __syncthreads();
    }

    const float4 es4 = *(const float4*)(esq + n0 + wn * 64 + j16 * 4);
    const size_t tbase = ((size_t)m0 + wm * 128) * 64 + (unsigned)(bn * 2 + wn);
#pragma unroll
    for (int mt = 0; mt < 8; ++mt) {
#pragma unroll
        for (int r = 0; r < 4; ++r) {
            float d0 = es4.x - 2.0f * acc[mt][0][r];
            float d1 = es4.y - 2.0f * acc[mt][1][r];
            float d2 = es4.z - 2.0f * acc[mt][2][r];
            float d3 = es4.w - 2.0f * acc[mt][3][r];
            float mn = fminf(fminf(d0, d1), fminf(d2, d3));
            mn = fminf(mn, __shfl_xor(mn, 1, 64));
            mn = fminf(mn, __shfl_xor(mn, 2, 64));
            mn = fminf(mn, __shfl_xor(mn, 4, 64));
            mn = fminf(mn, __shfl_xor(mn, 8, 64));
            if (j16 == 0)
                top1[tbase + (size_t)(mt * 16 + quad * 4 + r) * 64] = mn;
        }
    }
}

// ---------------- fused refine + gather: 1024 blocks x 16 rows ----------------
// Refine is lane-per-code: lane l verifies code g*64+l of each passing 64-group,
// reading h broadcast from LDS (wave-uniform address) and emb rows from L2.
__global__ __launch_bounds__(256) void k_finish(const float* __restrict__ h,
                                                const float* __restrict__ emb,
                                                const float* __restrict__ esq,
                                                const float* __restrict__ top1,
                                                float* __restrict__ out0,
                                                float* __restrict__ out1,
                                                float* __restrict__ plsum) {
    __shared__ __align__(16) float Sh[16][260];
    __shared__ __align__(16) float zq[16][260];
    __shared__ int idxs[16];
    __shared__ float wred[4];

    const int tid = threadIdx.x;
    const int lane = tid & 63;
    const int w = tid >> 6;
    const int n0 = blockIdx.x * 16;
    const int b = n0 >> 10;
    const int p0 = n0 & 1023;
    const size_t base = (size_t)b << 18;

    // phase 1: stage h coalesced (16 p x 16 c per iteration)
    {
        const int pp = tid & 15, c0 = tid >> 4;
#pragma unroll 4
        for (int it = 0; it < 16; ++it) {
            int c = it * 16 + c0;
            Sh[pp][c] = h[base + ((size_t)c << 10) + (size_t)(p0 + pp)];
        }
    }
    __syncthreads();

    // phase 2: refine rows w*4 .. w*4+3, lane-per-code
#pragma unroll 1
    for (int rr = 0; rr < 4; ++rr) {
        const int r = w * 4 + rr;
        const int n = n0 + r;
        const float gmv = top1[((size_t)n << 6) | (unsigned)lane];
        float m1 = gmv;
#pragma unroll
        for (int m = 32; m >= 1; m >>= 1) m1 = fminf(m1, __shfl_xor(m1, m, 64));
        unsigned long long mask = __ballot(gmv <= m1 + MARGIN);

        unsigned long long best = ~0ULL;
        while (mask) {
            const int g = __builtin_ctzll(mask);
            mask &= mask - 1;
            const int v = (g << 6) + lane;
            const float* er = emb + ((size_t)v << 8);
            float a0 = 0.f, a1 = 0.f, a2 = 0.f, a3 = 0.f;
#pragma unroll 4
            for (int c4 = 0; c4 < 16; ++c4) {
                float4 e0 = *(const float4*)(er + c4 * 16);
                float4 e1 = *(const float4*)(er + c4 * 16 + 4);
                float4 e2 = *(const float4*)(er + c4 * 16 + 8);
                float4 e3 = *(const float4*)(er + c4 * 16 + 12);
                float4 h0 = *(const float4*)&Sh[r][c4 * 16];
                float4 h1 = *(const float4*)&Sh[r][c4 * 16 + 4];
                float4 h2 = *(const float4*)&Sh[r][c4 * 16 + 8];
                float4 h3 = *(const float4*)&Sh[r][c4 * 16 + 12];
                a0 = fmaf(h0.x, e0.x, a0); a0 = fmaf(h0.y, e0.y, a0);
                a0 = fmaf(h0.z, e0.z, a0); a0 = fmaf(h0.w, e0.w, a0);
                a1 = fmaf(h1.x, e1.x, a1); a1 = fmaf(h1.y, e1.y, a1);
                a1 = fmaf(h1.z, e1.z, a1); a1 = fmaf(h1.w, e1.w, a1);
                a2 = fmaf(h2.x, e2.x, a2); a2 = fmaf(h2.y, e2.y, a2);
                a2 = fmaf(h2.z, e2.z, a2); a2 = fmaf(h2.w, e2.w, a2);
                a3 = fmaf(h3.x, e3.x, a3); a3 = fmaf(h3.y, e3.y, a3);
                a3 = fmaf(h3.z, e3.z, a3); a3 = fmaf(h3.w, e3.w, a3);
            }
            const float dot = (a0 + a1) + (a2 + a3);
            unsigned long long ke = pack_key(esq[v] - 2.0f * dot, v);
            best = ke < best ? ke : best;
        }
#pragma unroll
        for (int m = 32; m >= 1; m >>= 1) {
            unsigned long long o = __shfl_xor(best, m, 64);
            best = o < best ? o : best;
        }
        if (lane == 0) {
            const int idx = (int)(best & 0xFFFFFFFFULL);
            idxs[r] = idx;
            out1[n] = (float)idx;
        }
    }
    __syncthreads();

    // phase 3: gather z_q rows, write out0, loss partial
#pragma unroll
    for (int rr = 0; rr < 4; ++rr) {
        int r = w * 4 + rr;
        float4 e4 = *(const float4*)(emb + ((size_t)idxs[r] << 8) + lane * 4);
        *(float4*)&zq[r][lane * 4] = e4;
    }
    __syncthreads();

    float lsum = 0.0f;
    {
        const int pp = tid & 15, c0 = tid >> 4;
#pragma unroll 4
        for (int it = 0; it < 16; ++it) {
            int c = it * 16 + c0;
            float z = zq[pp][c];
            float hv = Sh[pp][c];
            out0[base + ((size_t)c << 10) + (size_t)(p0 + pp)] = hv + (z - hv);
            float d = hv - z;
            lsum = fmaf(d, d, lsum);
        }
    }
#pragma unroll
    for (int m = 32; m >= 1; m >>= 1) lsum += __shfl_xor(lsum, m, 64);
    if (lane == 0) wred[w] = lsum;
    __syncthreads();
    if (tid == 0) plsum[blockIdx.x] = wred[0] + wred[1] + wred[2] + wred[3];
}

// ---------------- final loss reduce (1024 partials) ----------------
__global__ __launch_bounds__(256) void k_fin(const float* __restrict__ plsum,
                                             float* __restrict__ out2) {
    __shared__ float wred[4];
    const int tid = threadIdx.x;
    float s = (plsum[tid] + plsum[tid + 256]) + (plsum[tid + 512] + plsum[tid + 768]);
#pragma unroll
    for (int m = 32; m >= 1; m >>= 1) s += __shfl_xor(s, m, 64);
    if ((tid & 63) == 0) wred[tid >> 6] = s;
    __syncthreads();
    if (tid == 0) out2[0] = (wred[0] + wred[1] + wred[2] + wred[3]) * (1.0f / (float)N_OUT0);
}

extern "C" void kernel_launch(void* const* d_in, const int* in_sizes, int n_in,
                              void* d_out, int out_size, void* d_ws, size_t ws_size,
                              hipStream_t stream) {
    const float* h = (const float*)d_in[0];
    const float* emb = (const float*)d_in[1];
    float* out0 = (float*)d_out;
    float* out1 = out0 + N_OUT0;
    float* out2 = out1 + NTOT;

    // ws layout (bytes), total ~14.3 MB < 21.1 MB available:
    char* w = (char*)d_ws;
    _Float16* Apk = (_Float16*)(w);            //  8 MB
    _Float16* Bpk = (_Float16*)(w + 8388608);  //  2 MB
    float* top1 = (float*)(w + 10485760);      //  4 MB (16384 x 64)
    float* esq = (float*)(w + 14680064);       // 16 KB
    float* plsum = (float*)(w + 14696448);     //  4 KB

    hipLaunchKernelGGL(k_pack, dim3(288), dim3(256), 0, stream, h, emb, Apk, Bpk, esq);
    hipLaunchKernelGGL(k_gemm, dim3(2048), dim3(256), 0, stream, Apk, Bpk, esq, top1);
    hipLaunchKernelGGL(k_finish, dim3(NTOT / 16), dim3(256), 0, stream, h, emb, esq, top1, out0, out1, plsum);
    hipLaunchKernelGGL(k_fin, dim3(1), dim3(256), 0, stream, plsum, out2);
}